// Round 8
// baseline (13.063 us; speedup 1.0000x reference)
//
#include <hip/hip_runtime.h>

#define NS 32
#define NH 32
#define C2L 2.8853900817779268f  // 2*log2(e): e^(2x) = 2^(C2L*x)

// 2 threads per point in 512-thread blocks: same block count (512) and same
// total staging work as the R7 1-thread/point kernel, but 4096 waves =
// 4 waves/SIMD (2x latency hiding). sub=tid&1 handles segments
// {s0+2*sub, s0+2*sub+1}, branchless; one shfl_xor combines.
// Padded LDS rows -> 2-way max bank alias on both staging writes and gathers.
__global__ __launch_bounds__(512, 4) void springnn_kernel(
    const float* __restrict__ t_in,
    const float* __restrict__ W1,   // [S][1][H]
    const float* __restrict__ b1,   // [S][H]
    const float* __restrict__ W2,   // [S][H][1]
    const float* __restrict__ b2,   // [S][1]
    float* __restrict__ out,
    int N)
{
    __shared__ float2 w1b1[NH][NS + 1];     // [h][s] = (W1*C2L, b1*C2L)
    __shared__ float2 w2p[NH / 2][NS + 1];  // [h2][s] = (-2*W2[2h2], -2*W2[2h2+1])
    __shared__ float  b2eff[NS];            // b2[s] + sum_h W2[s][h] (tanh folding)

    const int tid = threadIdx.x;

    // ---- stage: h-fast decode -> coalesced global; padded rows -> 2-way writes ----
    #pragma unroll
    for (int it = 0; it < 2; ++it) {
        const int idx = it * 512 + tid;
        const int s = idx >> 5;
        const int h = idx & 31;
        w1b1[h][s] = make_float2(W1[s * NH + h] * C2L, b1[s * NH + h] * C2L);
        ((float*)&w2p[h >> 1][s])[h & 1] = -2.0f * W2[s * NH + h];
    }
    if (tid < NS) {
        float acc = b2[tid];
        const float4* w2v = (const float4*)(W2 + tid * NH);
        #pragma unroll
        for (int q = 0; q < NH / 4; ++q) {
            float4 v = w2v[q];
            acc += (v.x + v.y) + (v.z + v.w);
        }
        b2eff[tid] = acc;
    }
    __syncthreads();

    const int gid = blockIdx.x * 512 + tid;
    const int n = gid >> 1;          // point index
    const int sub = tid & 1;         // segment-pair slot
    if (n >= N) return;
    const float t = t_in[n];

    // The only segments with w>0 are s0..s0+3 (d = t-s spans (-2,2]).
    const int sbase = (int)ceilf(t - 2.0f) + sub * 2;

    float val = 0.0f;
    #pragma unroll
    for (int j = 0; j < 2; ++j) {
        const int s = sbase + j;
        const bool ok = ((unsigned)s < (unsigned)NS);
        const int sc = ok ? s : 0;                       // clamped: reads unconditional
        // window = (1+cos(pi*d/2))/2 = cos^2(pi*d/4); v_cos takes revolutions
        const float c = __builtin_amdgcn_cosf((t - (float)s) * 0.125f);
        const float w = ok ? c * c : 0.0f;               // mask folded into weight

        float o0 = b2eff[sc], o1 = 0.0f;                 // 2 chains for ILP
        #pragma unroll
        for (int h2 = 0; h2 < NH / 2; ++h2) {
            const float2 wa = w1b1[2 * h2][sc];
            const float2 wb = w1b1[2 * h2 + 1][sc];
            const float2 wq = w2p[h2][sc];
            const float ea = __builtin_amdgcn_exp2f(fmaf(t, wa.x, wa.y));
            const float eb = __builtin_amdgcn_exp2f(fmaf(t, wb.x, wb.y));
            o0 = fmaf(wq.x, __builtin_amdgcn_rcpf(ea + 1.0f), o0);
            o1 = fmaf(wq.y, __builtin_amdgcn_rcpf(eb + 1.0f), o1);
        }
        val = fmaf(w, o0 + o1, val);
    }

    // combine the two segment-pair partials
    val += __shfl_xor(val, 1, 64);
    if (sub == 0) out[n] = val;
}

extern "C" void kernel_launch(void* const* d_in, const int* in_sizes, int n_in,
                              void* d_out, int out_size, void* d_ws, size_t ws_size,
                              hipStream_t stream) {
    const float* t  = (const float*)d_in[0];
    const float* W1 = (const float*)d_in[1];
    const float* b1 = (const float*)d_in[2];
    const float* W2 = (const float*)d_in[3];
    const float* b2 = (const float*)d_in[4];
    float* outp = (float*)d_out;
    const int N = in_sizes[0];

    const int block = 512;
    const long long threads = (long long)N * 2;
    const int grid = (int)((threads + block - 1) / block);
    springnn_kernel<<<grid, block, 0, stream>>>(t, W1, b1, W2, b2, outp, N);
}